// Round 1
// baseline (12378.361 us; speedup 1.0000x reference)
//
#include <hip/hip_runtime.h>
#include <cstddef>

// ---------------- problem constants ----------------
constexpr int CV    = 12000;  // vocab
constexpr int CWE   = 1000;   // word emb
constexpr int CFEAT = 2048;
constexpr int CFE   = 1024;
constexpr int CH    = 1024;
constexpr int CAH   = 512;
constexpr int CNREG = 36;
constexpr int CB    = 128;
constexpr int CT    = 17;
constexpr int XATT  = CH + CFE + CWE;   // 3048
constexpr int XLANG = CFE + CH;         // 2048
constexpr int G4    = 4 * CH;           // 4096

#define CDIV(a,b) (((a)+(b)-1)/(b))

// ---------------- fp32 tiled GEMM ----------------
// C[M,N] = act( sum_k A1[m,k]*W1(.,k or k,.) + [sum_k A2*W2] + bias1[n] + bias2[n] )
// TRANS_B: W is [N,K] row-major (torch Linear, A @ W^T). else W is [K,N] (A @ W).
constexpr int BM = 64, BN = 64, BK = 16;
constexpr int ASTR = BM + 4;   // padded LDS strides (bank-conflict)
constexpr int BSTR = BN + 4;

template<bool TRANS_B, bool DUAL, bool RELU>
__global__ __launch_bounds__(256)
void gemm_kernel(const float* __restrict__ A1, int lda1,
                 const float* __restrict__ W1, int ldw1, int K1,
                 const float* __restrict__ A2, int lda2,
                 const float* __restrict__ W2, int ldw2, int K2,
                 const float* __restrict__ bias1, const float* __restrict__ bias2,
                 float* __restrict__ C, int ldc, int M, int N)
{
    __shared__ float As[BK * ASTR];   // As[k][m]
    __shared__ float Bs[BK * BSTR];   // Bs[k][n]
    const int tid = threadIdx.x;
    const int tx = tid & 15, ty = tid >> 4;
    const int m0 = blockIdx.y * BM, n0 = blockIdx.x * BN;

    float acc[4][4] = {};

    const int nphase = DUAL ? 2 : 1;
    for (int phase = 0; phase < nphase; ++phase) {
        const float* A  = (DUAL && phase) ? A2  : A1;
        const float* W  = (DUAL && phase) ? W2  : W1;
        const int lda   = (DUAL && phase) ? lda2 : lda1;
        const int ldw   = (DUAL && phase) ? ldw2 : ldw1;
        const int K     = (DUAL && phase) ? K2  : K1;

        for (int k0 = 0; k0 < K; k0 += BK) {
            // ---- stage A tile (transposed into As[k][m]) ----
            {
                const int m  = tid >> 2;           // 0..63
                const int kq = (tid & 3) * 4;      // 0,4,8,12
                const int gm = m0 + m;
                float4 v = make_float4(0.f, 0.f, 0.f, 0.f);
                if (gm < M) {
                    if (k0 + BK <= K) {
                        v = *(const float4*)(A + (size_t)gm * lda + k0 + kq);
                    } else {
                        float t4[4] = {0.f,0.f,0.f,0.f};
                        #pragma unroll
                        for (int q = 0; q < 4; ++q)
                            if (k0 + kq + q < K) t4[q] = A[(size_t)gm * lda + k0 + kq + q];
                        v = make_float4(t4[0], t4[1], t4[2], t4[3]);
                    }
                }
                As[(kq + 0) * ASTR + m] = v.x;
                As[(kq + 1) * ASTR + m] = v.y;
                As[(kq + 2) * ASTR + m] = v.z;
                As[(kq + 3) * ASTR + m] = v.w;
            }
            // ---- stage B tile into Bs[k][n] ----
            if (TRANS_B) {
                const int n  = tid >> 2;           // 0..63
                const int kq = (tid & 3) * 4;
                const int gn = n0 + n;
                float4 v = make_float4(0.f, 0.f, 0.f, 0.f);
                if (gn < N) {
                    if (k0 + BK <= K) {
                        v = *(const float4*)(W + (size_t)gn * ldw + k0 + kq);
                    } else {
                        float t4[4] = {0.f,0.f,0.f,0.f};
                        #pragma unroll
                        for (int q = 0; q < 4; ++q)
                            if (k0 + kq + q < K) t4[q] = W[(size_t)gn * ldw + k0 + kq + q];
                        v = make_float4(t4[0], t4[1], t4[2], t4[3]);
                    }
                }
                Bs[(kq + 0) * BSTR + n] = v.x;
                Bs[(kq + 1) * BSTR + n] = v.y;
                Bs[(kq + 2) * BSTR + n] = v.z;
                Bs[(kq + 3) * BSTR + n] = v.w;
            } else {
                const int k  = tid >> 4;           // 0..15
                const int nq = (tid & 15) * 4;
                const int gk = k0 + k;
                float4 v = make_float4(0.f, 0.f, 0.f, 0.f);
                if (gk < K) {
                    if (n0 + nq + 3 < N) {
                        v = *(const float4*)(W + (size_t)gk * ldw + n0 + nq);
                    } else {
                        float t4[4] = {0.f,0.f,0.f,0.f};
                        #pragma unroll
                        for (int q = 0; q < 4; ++q)
                            if (n0 + nq + q < N) t4[q] = W[(size_t)gk * ldw + n0 + nq + q];
                        v = make_float4(t4[0], t4[1], t4[2], t4[3]);
                    }
                }
                *(float4*)&Bs[k * BSTR + nq] = v;
            }
            __syncthreads();
            // ---- compute ----
            #pragma unroll
            for (int kk = 0; kk < BK; ++kk) {
                float4 a = *(const float4*)&As[kk * ASTR + ty * 4];
                float4 b = *(const float4*)&Bs[kk * BSTR + tx * 4];
                float av[4] = {a.x, a.y, a.z, a.w};
                float bv[4] = {b.x, b.y, b.z, b.w};
                #pragma unroll
                for (int i = 0; i < 4; ++i)
                    #pragma unroll
                    for (int j = 0; j < 4; ++j)
                        acc[i][j] = fmaf(av[i], bv[j], acc[i][j]);
            }
            __syncthreads();
        }
    }

    // ---- epilogue ----
    #pragma unroll
    for (int i = 0; i < 4; ++i) {
        const int m = m0 + ty * 4 + i;
        if (m >= M) continue;
        #pragma unroll
        for (int j = 0; j < 4; ++j) {
            const int n = n0 + tx * 4 + j;
            if (n >= N) continue;
            float v = acc[i][j];
            if (bias1) v += bias1[n];
            if (bias2) v += bias2[n];
            if (RELU) v = fmaxf(v, 0.f);
            C[(size_t)m * ldc + n] = v;
        }
    }
}

// ---------------- embedding + relu into x_att[:, 2048:3048] ----------------
__global__ void emb_kernel(const float* __restrict__ emb_w,
                           const int* __restrict__ captions, int t,
                           float* __restrict__ x_att)
{
    const int b = blockIdx.y;
    const int j = blockIdx.x * 256 + threadIdx.x;
    if (j >= CWE) return;
    const int tok = captions[b * CT + t];
    const float v = emb_w[(size_t)tok * CWE + j];
    x_att[(size_t)b * XATT + (CH + CFE) + j] = fmaxf(v, 0.f);
}

// ---------------- LSTM pointwise ----------------
__global__ void lstm_kernel(const float* __restrict__ gates,
                            float* __restrict__ c,
                            float* __restrict__ h_out, int ld_h,
                            float* __restrict__ h_out2, int ld_h2)
{
    const int idx = blockIdx.x * 256 + threadIdx.x;
    if (idx >= CB * CH) return;
    const int b = idx >> 10, j = idx & (CH - 1);
    const float* g = gates + (size_t)b * G4;
    const float gi = g[j], gf = g[CH + j], gg = g[2 * CH + j], go = g[3 * CH + j];
    const float si = 1.f / (1.f + expf(-gi));
    const float sf = 1.f / (1.f + expf(-gf));
    const float so = 1.f / (1.f + expf(-go));
    const float cn = sf * c[idx] + si * tanhf(gg);
    const float hn = so * tanhf(cn);
    c[idx] = cn;
    h_out[(size_t)b * ld_h + j] = hn;
    if (h_out2) h_out2[(size_t)b * ld_h2 + j] = hn;
}

// ---------------- attention: e, softmax, weighted sum -> x_lang[:, 0:1024] --------
__global__ __launch_bounds__(256)
void attn_kernel(const float* __restrict__ p_att, const float* __restrict__ hq,
                 const float* __restrict__ att_e, const float* __restrict__ alpha_w,
                 const float* __restrict__ alpha_b, float* __restrict__ x_lang)
{
    __shared__ float shq[CAH];
    __shared__ float se[CNREG];
    __shared__ float salpha[CNREG];
    const int b = blockIdx.x;
    const int tid = threadIdx.x;

    for (int j = tid; j < CAH; j += 256) shq[j] = hq[b * CAH + j];
    __syncthreads();

    const int wave = tid >> 6, lane = tid & 63;
    for (int n = wave; n < CNREG; n += 4) {
        const float* pr = p_att + ((size_t)b * CNREG + n) * CAH;
        float s = 0.f;
        #pragma unroll
        for (int q = 0; q < CAH / 64; ++q) {
            const int d = lane + q * 64;
            s += alpha_w[d] * tanhf(pr[d] + shq[d]);
        }
        for (int off = 32; off; off >>= 1) s += __shfl_down(s, off);
        if (lane == 0) se[n] = s + alpha_b[0];
    }
    __syncthreads();

    float mx = -1e30f;
    for (int n = 0; n < CNREG; ++n) mx = fmaxf(mx, se[n]);
    float sum = 0.f;
    for (int n = 0; n < CNREG; ++n) sum += expf(se[n] - mx);
    const float inv = 1.f / sum;
    if (tid < CNREG) salpha[tid] = expf(se[tid] - mx) * inv;
    __syncthreads();

    for (int d = tid; d < CFE; d += 256) {
        float acc = 0.f;
        const float* ae = att_e + (size_t)b * CNREG * CFE + d;
        #pragma unroll 4
        for (int n = 0; n < CNREG; ++n) acc = fmaf(salpha[n], ae[(size_t)n * CFE], acc);
        x_lang[(size_t)b * XLANG + d] = acc;
    }
}

// ---------------- in-place log-softmax over V per row ----------------
__global__ __launch_bounds__(256)
void logsoftmax_kernel(float* __restrict__ x, int row_stride)
{
    __shared__ float red[4];
    const int b = blockIdx.x;
    float* row = x + (size_t)b * row_stride;
    const int tid = threadIdx.x;

    float mx = -1e30f;
    for (int j = tid; j < CV; j += 256) mx = fmaxf(mx, row[j]);
    for (int off = 32; off; off >>= 1) mx = fmaxf(mx, __shfl_down(mx, off));
    if ((tid & 63) == 0) red[tid >> 6] = mx;
    __syncthreads();
    mx = fmaxf(fmaxf(red[0], red[1]), fmaxf(red[2], red[3]));
    __syncthreads();

    float sum = 0.f;
    for (int j = tid; j < CV; j += 256) sum += expf(row[j] - mx);
    for (int off = 32; off; off >>= 1) sum += __shfl_down(sum, off);
    if ((tid & 63) == 0) red[tid >> 6] = sum;
    __syncthreads();
    sum = red[0] + red[1] + red[2] + red[3];
    const float lse = mx + logf(sum);

    for (int j = tid; j < CV; j += 256) row[j] -= lse;
}

// ---------------- launch ----------------
extern "C" void kernel_launch(void* const* d_in, const int* in_sizes, int n_in,
                              void* d_out, int out_size, void* d_ws, size_t ws_size,
                              hipStream_t stream)
{
    const float* fc_feats  = (const float*)d_in[0];
    const float* att_feats = (const float*)d_in[1];
    const int*   captions  = (const int*)  d_in[2];
    const float* emb_w     = (const float*)d_in[3];
    const float* fc_w      = (const float*)d_in[4];
    const float* fc_b      = (const float*)d_in[5];
    const float* atte_w    = (const float*)d_in[6];
    const float* atte_b    = (const float*)d_in[7];
    const float* ctx_w     = (const float*)d_in[8];
    const float* ctx_b     = (const float*)d_in[9];
    const float* attl_wih  = (const float*)d_in[10];
    const float* attl_whh  = (const float*)d_in[11];
    const float* attl_bih  = (const float*)d_in[12];
    const float* attl_bhh  = (const float*)d_in[13];
    const float* h2att_w   = (const float*)d_in[14];
    const float* h2att_b   = (const float*)d_in[15];
    const float* alpha_w   = (const float*)d_in[16];
    const float* alpha_b   = (const float*)d_in[17];
    const float* langl_wih = (const float*)d_in[18];
    const float* langl_whh = (const float*)d_in[19];
    const float* langl_bih = (const float*)d_in[20];
    const float* langl_bhh = (const float*)d_in[21];
    const float* cls_w     = (const float*)d_in[22];
    const float* cls_b     = (const float*)d_in[23];

    float* out = (float*)d_out;

    // workspace layout (floats)
    float* ws     = (float*)d_ws;
    float* att_e  = ws;                                 // [4608,1024]
    float* p_att  = att_e + (size_t)CB * CNREG * CFE;   // [4608,512]
    float* x_att  = p_att + (size_t)CB * CNREG * CAH;   // [128,3048]
    float* x_lang = x_att + (size_t)CB * XATT;          // [128,2048]
    float* gates  = x_lang + (size_t)CB * XLANG;        // [128,4096]
    float* h_att  = gates + (size_t)CB * G4;            // [128,1024]
    float* c_att  = h_att + (size_t)CB * CH;            // [128,1024]
    float* c_lang = c_att + (size_t)CB * CH;            // [128,1024]
    float* hq     = c_lang + (size_t)CB * CH;           // [128,512]

    // zero recurrent state + x_att (h_lang slot must be 0 at t=0)
    hipMemsetAsync(h_att,  0, (size_t)CB * CH * sizeof(float), stream);
    hipMemsetAsync(c_att,  0, (size_t)CB * CH * sizeof(float), stream);
    hipMemsetAsync(c_lang, 0, (size_t)CB * CH * sizeof(float), stream);
    hipMemsetAsync(x_att,  0, (size_t)CB * XATT * sizeof(float), stream);

    const dim3 blk(256);
    auto grid2 = [](int N, int M) { return dim3(CDIV(N, BN), CDIV(M, BM)); };

    // fc_e = relu(fc_feats @ fc_w + fc_b) -> x_att[:, 1024:2048]
    gemm_kernel<false,false,true><<<grid2(CFE, CB), blk, 0, stream>>>(
        fc_feats, CFEAT, fc_w, CFE, CFEAT,
        nullptr, 0, nullptr, 0, 0,
        fc_b, nullptr, x_att + CH, XATT, CB, CFE);

    // att_e = relu(att_feats @ atte_w + atte_b)   [4608,1024]
    gemm_kernel<false,false,true><<<grid2(CFE, CB*CNREG), blk, 0, stream>>>(
        att_feats, CFEAT, atte_w, CFE, CFEAT,
        nullptr, 0, nullptr, 0, 0,
        atte_b, nullptr, att_e, CFE, CB*CNREG, CFE);

    // p_att = att_e @ ctx_w + ctx_b   [4608,512]
    gemm_kernel<false,false,false><<<grid2(CAH, CB*CNREG), blk, 0, stream>>>(
        att_e, CFE, ctx_w, CAH, CFE,
        nullptr, 0, nullptr, 0, 0,
        ctx_b, nullptr, p_att, CAH, CB*CNREG, CAH);

    for (int t = 0; t < CT - 1; ++t) {
        // x_att[:, 2048:] = relu(emb_w[captions[:, t]])
        emb_kernel<<<dim3(CDIV(CWE, 256), CB), blk, 0, stream>>>(emb_w, captions, t, x_att);

        // att-LSTM gates = x_att @ wih^T + h_att @ whh^T + bih + bhh
        gemm_kernel<true,true,false><<<grid2(G4, CB), blk, 0, stream>>>(
            x_att, XATT, attl_wih, XATT, XATT,
            h_att, CH,   attl_whh, CH,   CH,
            attl_bih, attl_bhh, gates, G4, CB, G4);

        // pointwise: update c_att, h_att; copy h_att into x_lang[:,1024:2048]
        lstm_kernel<<<CDIV(CB*CH, 256), blk, 0, stream>>>(
            gates, c_att, h_att, CH, x_lang + CFE, XLANG);

        // hq = h_att @ h2att_w + h2att_b   [128,512]
        gemm_kernel<false,false,false><<<grid2(CAH, CB), blk, 0, stream>>>(
            h_att, CH, h2att_w, CAH, CH,
            nullptr, 0, nullptr, 0, 0,
            h2att_b, nullptr, hq, CAH, CB, CAH);

        // attention -> x_lang[:, 0:1024]
        attn_kernel<<<CB, blk, 0, stream>>>(p_att, hq, att_e, alpha_w, alpha_b, x_lang);

        // lang-LSTM gates = x_lang @ wih^T + h_lang @ whh^T + biases
        // (old h_lang lives in x_att[:, 0:1024])
        gemm_kernel<true,true,false><<<grid2(G4, CB), blk, 0, stream>>>(
            x_lang, XLANG, langl_wih, XLANG, XLANG,
            x_att,  XATT,  langl_whh, CH,   CH,
            langl_bih, langl_bhh, gates, G4, CB, G4);

        // pointwise: update c_lang; write new h_lang into x_att[:, 0:1024]
        lstm_kernel<<<CDIV(CB*CH, 256), blk, 0, stream>>>(
            gates, c_lang, x_att, XATT, nullptr, 0);

        // logits -> out[:, t, :]  (C row stride is (T-1)*V)
        gemm_kernel<false,false,false><<<grid2(CV, CB), blk, 0, stream>>>(
            x_att, XATT, cls_w, CV, CH,
            nullptr, 0, nullptr, 0, 0,
            cls_b, nullptr, out + (size_t)t * CV, (CT - 1) * CV, CB, CV);

        // in-place log-softmax
        logsoftmax_kernel<<<CB, blk, 0, stream>>>(out + (size_t)t * CV, (CT - 1) * CV);
    }
}

// Round 2
// 4095.798 us; speedup vs baseline: 3.0222x; 3.0222x over previous
//
#include <hip/hip_runtime.h>
#include <cstddef>
#include <cstdint>

// ---------------- problem constants ----------------
constexpr int CV    = 12000;
constexpr int CWE   = 1000;
constexpr int CFEAT = 2048;
constexpr int CFE   = 1024;
constexpr int CH    = 1024;
constexpr int CAH   = 512;
constexpr int CNREG = 36;
constexpr int CB    = 128;
constexpr int CT    = 17;
constexpr int XATT_P = 3072;            // 1024 h_lang | 1024 fc_e | 1000 emb | 24 zero-pad
constexpr int XLANG  = 2048;            // 1024 att_res | 1024 h_att
constexpr int G4     = 4096;

#define CDIV(a,b) (((a)+(b)-1)/(b))

typedef __bf16 bf16_t;
typedef __bf16 bf16x8 __attribute__((ext_vector_type(8)));
typedef float  f32x4  __attribute__((ext_vector_type(4)));

// ---------------- bf16 MFMA GEMM ----------------
// C[M,N] = act( A1 @ W1^T [+ A2 @ W2^T] + b1 [+ b2] )
// A: bf16 [M, lda] row-major. W: bf16 [N, ldw] row-major (pre-transposed weights).
// Block tile 64x32, 4 waves in 2x2, wave tile 32x16, mfma 16x16x32.
// Requires: M % 64 == 0, N % 32 == 0, K % 128 == 0 (pad with zeros).
template<bool DUAL, bool RELU, bool OUT_BF16>
__global__ __launch_bounds__(256)
void mfma_gemm(const bf16_t* __restrict__ A1, int lda1,
               const bf16_t* __restrict__ W1, int ldw1, int K1,
               const bf16_t* __restrict__ A2, int lda2,
               const bf16_t* __restrict__ W2, int ldw2, int K2,
               const float* __restrict__ bias1, const float* __restrict__ bias2,
               void* __restrict__ Cout, int ldc, int N)
{
    const int tid  = threadIdx.x;
    const int wid  = tid >> 6, lane = tid & 63;
    const int wr   = wid >> 1, wc = wid & 1;
    const int m0   = blockIdx.y * 64 + wr * 32;
    const int n0   = blockIdx.x * 32 + wc * 16;
    const int lhi  = lane >> 4, llo = lane & 15;

    f32x4 acc0 = {0.f, 0.f, 0.f, 0.f};
    f32x4 acc1 = {0.f, 0.f, 0.f, 0.f};

    const int nphase = DUAL ? 2 : 1;
    for (int phase = 0; phase < nphase; ++phase) {
        const bf16_t* A  = (DUAL && phase) ? A2   : A1;
        const bf16_t* W  = (DUAL && phase) ? W2   : W1;
        const int lda    = (DUAL && phase) ? lda2 : lda1;
        const int ldw    = (DUAL && phase) ? ldw2 : ldw1;
        const int K      = (DUAL && phase) ? K2   : K1;

        const bf16_t* pa0 = A + (size_t)(m0 + llo)      * lda + lhi * 8;
        const bf16_t* pa1 = A + (size_t)(m0 + 16 + llo) * lda + lhi * 8;
        const bf16_t* pb  = W + (size_t)(n0 + llo)      * ldw + lhi * 8;

        #pragma unroll 4
        for (int k = 0; k < K; k += 32) {
            bf16x8 a0 = *(const bf16x8*)(pa0 + k);
            bf16x8 a1 = *(const bf16x8*)(pa1 + k);
            bf16x8 b  = *(const bf16x8*)(pb  + k);
            acc0 = __builtin_amdgcn_mfma_f32_16x16x32_bf16(a0, b, acc0, 0, 0, 0);
            acc1 = __builtin_amdgcn_mfma_f32_16x16x32_bf16(a1, b, acc1, 0, 0, 0);
        }
    }

    // epilogue: C/D layout col = lane&15, row = (lane>>4)*4 + reg
    const int col = n0 + llo;
    float bsum = 0.f;
    if (bias1) bsum += bias1[col];
    if (bias2) bsum += bias2[col];
    #pragma unroll
    for (int mt = 0; mt < 2; ++mt) {
        f32x4 a = mt ? acc1 : acc0;
        #pragma unroll
        for (int r = 0; r < 4; ++r) {
            const int row = m0 + mt * 16 + lhi * 4 + r;
            float v = a[r] + bsum;
            if (RELU) v = fmaxf(v, 0.f);
            if (OUT_BF16) ((bf16_t*)Cout)[(size_t)row * ldc + col] = (bf16_t)v;
            else          ((float*) Cout)[(size_t)row * ldc + col] = v;
        }
    }
}

// ---------------- fp32 -> bf16 convert with column pad ----------------
__global__ void convert_pad(const float* __restrict__ src, bf16_t* __restrict__ dst,
                            int C, int Cp)
{
    const int r = blockIdx.y;
    const int c = blockIdx.x * 256 + threadIdx.x;
    if (c >= Cp) return;
    dst[(size_t)r * Cp + c] = (c < C) ? (bf16_t)src[(size_t)r * C + c] : (bf16_t)0.f;
}

// ---------------- fp32 [K,N] -> bf16 [N,K] transpose-convert ----------------
__global__ __launch_bounds__(256)
void transpose_convert(const float* __restrict__ src, bf16_t* __restrict__ dst,
                       int K, int N)
{
    __shared__ float tile[32][33];
    const int n0 = blockIdx.x * 32, k0 = blockIdx.y * 32;
    const int tx = threadIdx.x & 31, ty = threadIdx.x >> 5;   // 32 x 8
    #pragma unroll
    for (int i = 0; i < 4; ++i) {
        const int k = k0 + ty + i * 8, n = n0 + tx;
        tile[ty + i * 8][tx] = (k < K && n < N) ? src[(size_t)k * N + n] : 0.f;
    }
    __syncthreads();
    #pragma unroll
    for (int i = 0; i < 4; ++i) {
        const int n = n0 + ty + i * 8, k = k0 + tx;
        if (n < N && k < K) dst[(size_t)n * K + k] = (bf16_t)tile[tx][ty + i * 8];
    }
}

// ---------------- embedding + relu -> x_att[:, 2048:3048] (bf16) ----------------
__global__ void emb_kernel(const float* __restrict__ emb_w,
                           const int* __restrict__ captions, int t,
                           bf16_t* __restrict__ x_att)
{
    const int b = blockIdx.y;
    const int j = blockIdx.x * 256 + threadIdx.x;
    if (j >= CWE) return;
    const int tok = captions[b * CT + t];
    const float v = fmaxf(emb_w[(size_t)tok * CWE + j], 0.f);
    x_att[(size_t)b * XATT_P + 2048 + j] = (bf16_t)v;
}

// ---------------- LSTM pointwise: gates fp32 -> c fp32, h bf16 (x2) -------------
__global__ void lstm_kernel(const float* __restrict__ gates, float* __restrict__ c,
                            bf16_t* __restrict__ h1, int ld1,
                            bf16_t* __restrict__ h2, int ld2)
{
    const int idx = blockIdx.x * 256 + threadIdx.x;
    if (idx >= CB * CH) return;
    const int b = idx >> 10, j = idx & (CH - 1);
    const float* g = gates + (size_t)b * G4;
    const float gi = g[j], gf = g[CH + j], gg = g[2 * CH + j], go = g[3 * CH + j];
    const float si = 1.f / (1.f + expf(-gi));
    const float sf = 1.f / (1.f + expf(-gf));
    const float so = 1.f / (1.f + expf(-go));
    const float cn = sf * c[idx] + si * tanhf(gg);
    const float hn = so * tanhf(cn);
    c[idx] = cn;
    const bf16_t hb = (bf16_t)hn;
    h1[(size_t)b * ld1 + j] = hb;
    if (h2) h2[(size_t)b * ld2 + j] = hb;
}

// -------- attention (hq fused): e, softmax, weighted-sum -> x_lang[:,0:1024] ----
__global__ __launch_bounds__(256)
void attn_kernel(const float* __restrict__ p_att, const bf16_t* __restrict__ h_att,
                 const bf16_t* __restrict__ h2att_wT, const float* __restrict__ h2att_b,
                 const bf16_t* __restrict__ att_e, const float* __restrict__ alpha_w,
                 const float* __restrict__ alpha_b, bf16_t* __restrict__ x_lang)
{
    __shared__ float sh[CH];
    __shared__ float shq[CAH];
    __shared__ float se[CNREG];
    __shared__ float salpha[CNREG];
    const int b = blockIdx.x, tid = threadIdx.x;

    for (int j = tid; j < CH; j += 256) sh[j] = (float)h_att[(size_t)b * CH + j];
    __syncthreads();

    // hq[n] = h_att[b] . h2att_wT[n,:] + h2att_b[n]
    for (int n = tid; n < CAH; n += 256) {
        const bf16_t* wrow = h2att_wT + (size_t)n * CH;
        float s = 0.f;
        for (int k = 0; k < CH; k += 8) {
            bf16x8 wv = *(const bf16x8*)(wrow + k);
            #pragma unroll
            for (int q = 0; q < 8; ++q) s = fmaf((float)wv[q], sh[k + q], s);
        }
        shq[n] = s + h2att_b[n];
    }
    __syncthreads();

    const int wave = tid >> 6, lane = tid & 63;
    for (int n = wave; n < CNREG; n += 4) {
        const float* pr = p_att + ((size_t)b * CNREG + n) * CAH;
        float s = 0.f;
        #pragma unroll
        for (int q = 0; q < CAH / 64; ++q) {
            const int d = lane + q * 64;
            s += alpha_w[d] * tanhf(pr[d] + shq[d]);
        }
        for (int off = 32; off; off >>= 1) s += __shfl_down(s, off);
        if (lane == 0) se[n] = s + alpha_b[0];
    }
    __syncthreads();

    float mx = -1e30f;
    for (int n = 0; n < CNREG; ++n) mx = fmaxf(mx, se[n]);
    float sum = 0.f;
    for (int n = 0; n < CNREG; ++n) sum += expf(se[n] - mx);
    const float inv = 1.f / sum;
    if (tid < CNREG) salpha[tid] = expf(se[tid] - mx) * inv;
    __syncthreads();

    for (int d = tid; d < CFE; d += 256) {
        float s = 0.f;
        const bf16_t* ae = att_e + (size_t)b * CNREG * CFE + d;
        #pragma unroll 4
        for (int n = 0; n < CNREG; ++n) s = fmaf(salpha[n], (float)ae[(size_t)n * CFE], s);
        x_lang[(size_t)b * XLANG + d] = (bf16_t)s;
    }
}

// ---------------- in-place log-softmax over V per row (fp32) ----------------
__global__ __launch_bounds__(256)
void logsoftmax_kernel(float* __restrict__ x, int row_stride)
{
    __shared__ float red[4];
    const int b = blockIdx.x;
    float* row = x + (size_t)b * row_stride;
    const int tid = threadIdx.x;

    float mx = -1e30f;
    for (int j = tid; j < CV; j += 256) mx = fmaxf(mx, row[j]);
    for (int off = 32; off; off >>= 1) mx = fmaxf(mx, __shfl_down(mx, off));
    if ((tid & 63) == 0) red[tid >> 6] = mx;
    __syncthreads();
    mx = fmaxf(fmaxf(red[0], red[1]), fmaxf(red[2], red[3]));
    __syncthreads();

    float sum = 0.f;
    for (int j = tid; j < CV; j += 256) sum += expf(row[j] - mx);
    for (int off = 32; off; off >>= 1) sum += __shfl_down(sum, off);
    if ((tid & 63) == 0) red[tid >> 6] = sum;
    __syncthreads();
    sum = red[0] + red[1] + red[2] + red[3];
    const float lse = mx + logf(sum);

    for (int j = tid; j < CV; j += 256) row[j] -= lse;
}

// ---------------- launch ----------------
extern "C" void kernel_launch(void* const* d_in, const int* in_sizes, int n_in,
                              void* d_out, int out_size, void* d_ws, size_t ws_size,
                              hipStream_t stream)
{
    const float* fc_feats  = (const float*)d_in[0];
    const float* att_feats = (const float*)d_in[1];
    const int*   captions  = (const int*)  d_in[2];
    const float* emb_w     = (const float*)d_in[3];
    const float* fc_w      = (const float*)d_in[4];
    const float* fc_b      = (const float*)d_in[5];
    const float* atte_w    = (const float*)d_in[6];
    const float* atte_b    = (const float*)d_in[7];
    const float* ctx_w     = (const float*)d_in[8];
    const float* ctx_b     = (const float*)d_in[9];
    const float* attl_wih  = (const float*)d_in[10];
    const float* attl_whh  = (const float*)d_in[11];
    const float* attl_bih  = (const float*)d_in[12];
    const float* attl_bhh  = (const float*)d_in[13];
    const float* h2att_w   = (const float*)d_in[14];
    const float* h2att_b   = (const float*)d_in[15];
    const float* alpha_w   = (const float*)d_in[16];
    const float* alpha_b   = (const float*)d_in[17];
    const float* langl_wih = (const float*)d_in[18];
    const float* langl_whh = (const float*)d_in[19];
    const float* langl_bih = (const float*)d_in[20];
    const float* langl_bhh = (const float*)d_in[21];
    const float* cls_w     = (const float*)d_in[22];
    const float* cls_b     = (const float*)d_in[23];

    float* out = (float*)d_out;

    // ---- workspace layout ----
    char* p = (char*)d_ws;
    auto alloc_bf = [&](size_t elems) { bf16_t* q = (bf16_t*)p; p += elems * 2; return q; };
    auto alloc_f  = [&](size_t elems) { float*  q = (float*) p; p += elems * 4; return q; };

    bf16_t* attl_wih_b  = alloc_bf((size_t)G4 * XATT_P);    // [4096,3072] padded
    bf16_t* attl_whh_b  = alloc_bf((size_t)G4 * CH);
    bf16_t* langl_wih_b = alloc_bf((size_t)G4 * XLANG);
    bf16_t* langl_whh_b = alloc_bf((size_t)G4 * CH);
    bf16_t* fc_wT_b     = alloc_bf((size_t)CFE * CFEAT);    // [1024,2048]
    bf16_t* atte_wT_b   = alloc_bf((size_t)CFE * CFEAT);
    bf16_t* ctx_wT_b    = alloc_bf((size_t)CAH * CFE);      // [512,1024]
    bf16_t* h2att_wT_b  = alloc_bf((size_t)CAH * CH);       // [512,1024]
    bf16_t* cls_wT_b    = alloc_bf((size_t)CV * CH);        // [12000,1024]
    bf16_t* fc_feats_b  = alloc_bf((size_t)CB * CFEAT);
    bf16_t* att_feats_b = alloc_bf((size_t)CB * CNREG * CFEAT);
    bf16_t* att_e_b     = alloc_bf((size_t)CB * CNREG * CFE);
    bf16_t* x_att       = alloc_bf((size_t)CB * XATT_P);
    bf16_t* x_lang      = alloc_bf((size_t)CB * XLANG);
    bf16_t* h_att_b     = alloc_bf((size_t)CB * CH);
    float*  p_att       = alloc_f ((size_t)CB * CNREG * CAH);
    float*  gates       = alloc_f ((size_t)CB * G4);
    float*  c_att       = alloc_f ((size_t)CB * CH);
    float*  c_lang      = alloc_f ((size_t)CB * CH);

    // ---- zero recurrent state (h_lang slot + pad in x_att must be 0) ----
    hipMemsetAsync(x_att,   0, (size_t)CB * XATT_P * 2, stream);
    hipMemsetAsync(h_att_b, 0, (size_t)CB * CH * 2, stream);
    hipMemsetAsync(c_att,   0, (size_t)CB * CH * 4, stream);
    hipMemsetAsync(c_lang,  0, (size_t)CB * CH * 4, stream);

    const dim3 blk(256);

    // ---- one-time conversions ----
    convert_pad<<<dim3(CDIV(XATT_P,256), G4), blk, 0, stream>>>(attl_wih, attl_wih_b, XATT_P-24, XATT_P);
    convert_pad<<<dim3(CDIV(CH,256),    G4), blk, 0, stream>>>(attl_whh, attl_whh_b, CH, CH);
    convert_pad<<<dim3(CDIV(XLANG,256), G4), blk, 0, stream>>>(langl_wih, langl_wih_b, XLANG, XLANG);
    convert_pad<<<dim3(CDIV(CH,256),    G4), blk, 0, stream>>>(langl_whh, langl_whh_b, CH, CH);
    convert_pad<<<dim3(CDIV(CFEAT,256), CB), blk, 0, stream>>>(fc_feats, fc_feats_b, CFEAT, CFEAT);
    convert_pad<<<dim3(CDIV(CFEAT,256), CB*CNREG), blk, 0, stream>>>(att_feats, att_feats_b, CFEAT, CFEAT);
    transpose_convert<<<dim3(CFE/32,  CFEAT/32), blk, 0, stream>>>(fc_w,    fc_wT_b,    CFEAT, CFE);
    transpose_convert<<<dim3(CFE/32,  CFEAT/32), blk, 0, stream>>>(atte_w,  atte_wT_b,  CFEAT, CFE);
    transpose_convert<<<dim3(CAH/32,  CFE/32),   blk, 0, stream>>>(ctx_w,   ctx_wT_b,   CFE,   CAH);
    transpose_convert<<<dim3(CAH/32,  CH/32),    blk, 0, stream>>>(h2att_w, h2att_wT_b, CH,    CAH);
    transpose_convert<<<dim3(CV/32,   CH/32),    blk, 0, stream>>>(cls_w,   cls_wT_b,   CH,    CV);

    // ---- preamble GEMMs ----
    // fc_e = relu(fc_feats @ fc_w + fc_b) -> x_att[:, 1024:2048] (bf16)
    mfma_gemm<false,true,true><<<dim3(CFE/32, CB/64), blk, 0, stream>>>(
        fc_feats_b, CFEAT, fc_wT_b, CFEAT, CFEAT,
        nullptr, 0, nullptr, 0, 0, fc_b, nullptr, x_att + CH, XATT_P, CFE);
    // att_e = relu(att_feats @ atte_w + atte_b) (bf16) [4608,1024]
    mfma_gemm<false,true,true><<<dim3(CFE/32, CB*CNREG/64), blk, 0, stream>>>(
        att_feats_b, CFEAT, atte_wT_b, CFEAT, CFEAT,
        nullptr, 0, nullptr, 0, 0, atte_b, nullptr, att_e_b, CFE, CFE);
    // p_att = att_e @ ctx_w + ctx_b (fp32) [4608,512]
    mfma_gemm<false,false,false><<<dim3(CAH/32, CB*CNREG/64), blk, 0, stream>>>(
        att_e_b, CFE, ctx_wT_b, CFE, CFE,
        nullptr, 0, nullptr, 0, 0, ctx_b, nullptr, p_att, CAH, CAH);

    for (int t = 0; t < CT - 1; ++t) {
        emb_kernel<<<dim3(CDIV(CWE,256), CB), blk, 0, stream>>>(emb_w, captions, t, x_att);

        // att-LSTM gates = x_att @ wih^T + h_att @ whh^T + biases (fp32)
        mfma_gemm<true,false,false><<<dim3(G4/32, CB/64), blk, 0, stream>>>(
            x_att, XATT_P, attl_wih_b, XATT_P, XATT_P,
            h_att_b, CH, attl_whh_b, CH, CH,
            attl_bih, attl_bhh, gates, G4, G4);

        // update c_att; h_att (bf16) + copy into x_lang[:,1024:2048]
        lstm_kernel<<<CDIV(CB*CH,256), blk, 0, stream>>>(
            gates, c_att, h_att_b, CH, x_lang + CFE, XLANG);

        // attention (hq fused) -> x_lang[:, 0:1024] (bf16)
        attn_kernel<<<CB, blk, 0, stream>>>(
            p_att, h_att_b, h2att_wT_b, h2att_b, att_e_b, alpha_w, alpha_b, x_lang);

        // lang-LSTM gates = x_lang @ wih^T + h_lang @ whh^T + biases
        // (old h_lang lives in x_att[:, 0:1024])
        mfma_gemm<true,false,false><<<dim3(G4/32, CB/64), blk, 0, stream>>>(
            x_lang, XLANG, langl_wih_b, XLANG, XLANG,
            x_att, XATT_P, langl_whh_b, CH, CH,
            langl_bih, langl_bhh, gates, G4, G4);

        // update c_lang; new h_lang -> x_att[:, 0:1024] (bf16)
        lstm_kernel<<<CDIV(CB*CH,256), blk, 0, stream>>>(
            gates, c_lang, x_att, XATT_P, nullptr, 0);

        // logits = h_lang @ cls_w + cls_b -> out[:, t, :] (fp32)
        mfma_gemm<false,false,false><<<dim3(CV/32, CB/64), blk, 0, stream>>>(
            x_att, XATT_P, cls_wT_b, CH, CH,
            nullptr, 0, nullptr, 0, 0, cls_b, nullptr,
            out + (size_t)t * CV, (CT - 1) * CV, CV);

        logsoftmax_kernel<<<CB, blk, 0, stream>>>(out + (size_t)t * CV, (CT - 1) * CV);
    }
}

// Round 3
// 3547.257 us; speedup vs baseline: 3.4896x; 1.1546x over previous
//
#include <hip/hip_runtime.h>
#include <cstddef>
#include <cstdint>

// ---------------- problem constants ----------------
constexpr int CV    = 12000;
constexpr int CVP   = 12032;   // vocab padded to x64
constexpr int CWE   = 1000;
constexpr int CFEAT = 2048;
constexpr int CFE   = 1024;
constexpr int CH    = 1024;
constexpr int CAH   = 512;
constexpr int CNREG = 36;
constexpr int CB    = 128;
constexpr int CT    = 17;
constexpr int XATT_P = 3072;   // 1024 h_lang | 1024 fc_e | 1000 emb | 24 zero-pad
constexpr int XLANG  = 2048;   // 1024 att_res | 1024 h_att
constexpr int G4     = 4096;

#define CDIV(a,b) (((a)+(b)-1)/(b))

typedef __bf16 bf16_t;
typedef __bf16 bf16x8 __attribute__((ext_vector_type(8)));
typedef float  f32x4  __attribute__((ext_vector_type(4)));

// ---------------- LDS-staged, double-buffered MFMA GEMM ----------------
// C[M,N] = A @ W^T (+ A2 @ W2^T) + bias1 + bias2, optional ReLU / bf16 out.
// A bf16 [M,lda] row-major; W bf16 [N,ldw] row-major (pre-transposed weights).
// Requires M%128==0, N%64==0, K%64==0. Block 128x64, 4 waves 2x2, wave 64x32.
// gridDim.z = NSPLIT deterministic split-K: z writes fp32 partial at
// Cout + z*partStride (bias folded into z==0); consumers sum partials.
// LDS: per buffer A[128][64] + B[64][64] bf16, 16B chunks XOR-swizzled by row&7.
template<bool DUAL, bool RELU, bool OUTBF>
__global__ __launch_bounds__(256)
void gemm2(const bf16_t* __restrict__ A1, int lda1,
           const bf16_t* __restrict__ W1, int ldw1, int K1,
           const bf16_t* __restrict__ A2, int lda2,
           const bf16_t* __restrict__ W2, int ldw2, int K2,
           const float* __restrict__ bias1, const float* __restrict__ bias2,
           void* __restrict__ Cout, int ldc, size_t partStride)
{
    const int tid = threadIdx.x;
    const int wid = tid >> 6, lane = tid & 63;
    const int wr = wid >> 1, wc = wid & 1;
    const int llo = lane & 15, lhi = lane >> 4;
    const int m0 = blockIdx.y * 128, n0 = blockIdx.x * 64;
    const int z = blockIdx.z, ns = gridDim.z;

    __shared__ __align__(16) uint8_t sm[2][24576];  // A [0,16384) | B [16384,24576)

    const int T1 = K1 >> 6;
    const int TT = T1 + (DUAL ? (K2 >> 6) : 0);
    const int tb = (int)(((long)TT * z) / ns), te = (int)(((long)TT * (z + 1)) / ns);

    f32x4 acc[4][2] = {};
    uint4 ra[4], rb[2];

    const int srow = tid >> 3;          // 0..31
    const int sc   = tid & 7;           // 16B chunk index
    const int cswz = (sc ^ (srow & 7)) << 4;

    auto load_tile = [&](int ti) {
        const bf16_t *As, *Ws; int la, lw, k0;
        if (!DUAL || ti < T1) { As = A1; la = lda1; Ws = W1; lw = ldw1; k0 = ti << 6; }
        else                  { As = A2; la = lda2; Ws = W2; lw = ldw2; k0 = (ti - T1) << 6; }
        #pragma unroll
        for (int i = 0; i < 4; ++i) {
            const int row = i * 32 + srow;
            ra[i] = *(const uint4*)(As + (size_t)(m0 + row) * la + k0 + sc * 8);
        }
        #pragma unroll
        for (int i = 0; i < 2; ++i) {
            const int row = i * 32 + srow;
            rb[i] = *(const uint4*)(Ws + (size_t)(n0 + row) * lw + k0 + sc * 8);
        }
    };
    auto write_tile = [&](int buf) {
        uint8_t* base = sm[buf];
        #pragma unroll
        for (int i = 0; i < 4; ++i)
            *(uint4*)(base + (i * 32 + srow) * 128 + cswz) = ra[i];
        #pragma unroll
        for (int i = 0; i < 2; ++i)
            *(uint4*)(base + 16384 + (i * 32 + srow) * 128 + cswz) = rb[i];
    };
    auto compute = [&](int buf) {
        const uint8_t* base = sm[buf];
        const int r7 = llo & 7;
        #pragma unroll
        for (int kk = 0; kk < 2; ++kk) {
            const int cp = kk * 4 + lhi;          // k-chunk (permuted-k, same for A & B)
            const int coff = ((cp ^ r7) << 4);
            bf16x8 af[4], bg[2];
            #pragma unroll
            for (int fm = 0; fm < 4; ++fm)
                af[fm] = *(const bf16x8*)(base + (wr * 64 + fm * 16 + llo) * 128 + coff);
            #pragma unroll
            for (int fn = 0; fn < 2; ++fn)
                bg[fn] = *(const bf16x8*)(base + 16384 + (wc * 32 + fn * 16 + llo) * 128 + coff);
            #pragma unroll
            for (int fm = 0; fm < 4; ++fm)
                #pragma unroll
                for (int fn = 0; fn < 2; ++fn)
                    acc[fm][fn] = __builtin_amdgcn_mfma_f32_16x16x32_bf16(
                        af[fm], bg[fn], acc[fm][fn], 0, 0, 0);
        }
    };

    load_tile(tb);
    write_tile(0);
    __syncthreads();
    int cur = 0;
    for (int ti = tb; ti < te; ++ti) {
        const bool more = (ti + 1 < te);
        if (more) load_tile(ti + 1);     // issue loads; vmcnt waited only at write
        compute(cur);
        __syncthreads();
        if (more) write_tile(cur ^ 1);
        __syncthreads();
        cur ^= 1;
    }

    // epilogue: C/D layout col = lane&15, row = (lane>>4)*4 + reg
    const int colb = n0 + wc * 32;
    const int rowb = m0 + wr * 64 + lhi * 4;
    if (ns > 1) {
        float* Cp = (float*)Cout + (size_t)z * partStride;
        #pragma unroll
        for (int fn = 0; fn < 2; ++fn) {
            const int col = colb + fn * 16 + llo;
            const float b = (z == 0) ? ((bias1 ? bias1[col] : 0.f) + (bias2 ? bias2[col] : 0.f)) : 0.f;
            #pragma unroll
            for (int fm = 0; fm < 4; ++fm)
                #pragma unroll
                for (int r = 0; r < 4; ++r)
                    Cp[(size_t)(rowb + fm * 16 + r) * ldc + col] = acc[fm][fn][r] + b;
        }
    } else {
        #pragma unroll
        for (int fn = 0; fn < 2; ++fn) {
            const int col = colb + fn * 16 + llo;
            float b = 0.f;
            if (bias1) b += bias1[col];
            if (bias2) b += bias2[col];
            #pragma unroll
            for (int fm = 0; fm < 4; ++fm)
                #pragma unroll
                for (int r = 0; r < 4; ++r) {
                    float v = acc[fm][fn][r] + b;
                    if (RELU) v = fmaxf(v, 0.f);
                    const size_t off = (size_t)(rowb + fm * 16 + r) * ldc + col;
                    if (OUTBF) ((bf16_t*)Cout)[off] = (bf16_t)v;
                    else       ((float*) Cout)[off] = v;
                }
        }
    }
}

// ---------------- fp32 -> bf16 convert with column pad ----------------
__global__ void convert_pad(const float* __restrict__ src, bf16_t* __restrict__ dst,
                            int C, int Cp)
{
    const int r = blockIdx.y;
    const int c = blockIdx.x * 256 + threadIdx.x;
    if (c >= Cp) return;
    dst[(size_t)r * Cp + c] = (c < C) ? (bf16_t)src[(size_t)r * C + c] : (bf16_t)0.f;
}

// ---------------- fp32 [K,N] -> bf16 [N,K] transpose-convert ----------------
__global__ __launch_bounds__(256)
void transpose_convert(const float* __restrict__ src, bf16_t* __restrict__ dst,
                       int K, int N)
{
    __shared__ float tile[32][33];
    const int n0 = blockIdx.x * 32, k0 = blockIdx.y * 32;
    const int tx = threadIdx.x & 31, ty = threadIdx.x >> 5;   // 32 x 8
    #pragma unroll
    for (int i = 0; i < 4; ++i) {
        const int k = k0 + ty + i * 8, n = n0 + tx;
        tile[ty + i * 8][tx] = (k < K && n < N) ? src[(size_t)k * N + n] : 0.f;
    }
    __syncthreads();
    #pragma unroll
    for (int i = 0; i < 4; ++i) {
        const int n = n0 + ty + i * 8, k = k0 + tx;
        if (n < N && k < K) dst[(size_t)n * K + k] = (bf16_t)tile[tx][ty + i * 8];
    }
}

// ---------------- embedding + relu -> x_att[:, 2048:3048] (bf16) ----------------
__global__ void emb_kernel(const float* __restrict__ emb_w,
                           const int* __restrict__ captions, int t,
                           bf16_t* __restrict__ x_att)
{
    const int b = blockIdx.y;
    const int j = blockIdx.x * 256 + threadIdx.x;
    if (j >= CWE) return;
    const int tok = captions[b * CT + t];
    const float v = fmaxf(emb_w[(size_t)tok * CWE + j], 0.f);
    x_att[(size_t)b * XATT_P + 2048 + j] = (bf16_t)v;
}

// ------------- LSTM pointwise: sum gate partials -> c fp32, h bf16 (x2) ---------
__global__ void lstm_kernel(const float* __restrict__ gpart, int npart,
                            float* __restrict__ c,
                            bf16_t* __restrict__ h1, int ld1,
                            bf16_t* __restrict__ h2, int ld2)
{
    const int idx = blockIdx.x * 256 + threadIdx.x;
    if (idx >= CB * CH) return;
    const int b = idx >> 10, j = idx & (CH - 1);
    float gi = 0.f, gf = 0.f, gg = 0.f, go = 0.f;
    for (int zp = 0; zp < npart; ++zp) {
        const float* g = gpart + (size_t)zp * CB * G4 + (size_t)b * G4;
        gi += g[j]; gf += g[CH + j]; gg += g[2 * CH + j]; go += g[3 * CH + j];
    }
    const float si = 1.f / (1.f + expf(-gi));
    const float sf = 1.f / (1.f + expf(-gf));
    const float so = 1.f / (1.f + expf(-go));
    const float cn = sf * c[idx] + si * tanhf(gg);
    const float hn = so * tanhf(cn);
    c[idx] = cn;
    const bf16_t hb = (bf16_t)hn;
    h1[(size_t)b * ld1 + j] = hb;
    if (h2) h2[(size_t)b * ld2 + j] = hb;
}

// -------- attention (hq fused): e, softmax, weighted-sum -> x_lang[:,0:1024] ----
__global__ __launch_bounds__(256)
void attn_kernel(const float* __restrict__ p_att, const bf16_t* __restrict__ h_att,
                 const bf16_t* __restrict__ h2att_wT, const float* __restrict__ h2att_b,
                 const bf16_t* __restrict__ att_e, const float* __restrict__ alpha_w,
                 const float* __restrict__ alpha_b, bf16_t* __restrict__ x_lang)
{
    __shared__ float sh[CH];
    __shared__ float shq[CAH];
    __shared__ float se[CNREG];
    __shared__ float salpha[CNREG];
    const int b = blockIdx.x, tid = threadIdx.x;

    for (int j = tid; j < CH; j += 256) sh[j] = (float)h_att[(size_t)b * CH + j];
    __syncthreads();

    for (int n = tid; n < CAH; n += 256) {
        const bf16_t* wrow = h2att_wT + (size_t)n * CH;
        float s = 0.f;
        for (int k = 0; k < CH; k += 8) {
            bf16x8 wv = *(const bf16x8*)(wrow + k);
            #pragma unroll
            for (int q = 0; q < 8; ++q) s = fmaf((float)wv[q], sh[k + q], s);
        }
        shq[n] = s + h2att_b[n];
    }
    __syncthreads();

    const int wave = tid >> 6, lane = tid & 63;
    for (int n = wave; n < CNREG; n += 4) {
        const float* pr = p_att + ((size_t)b * CNREG + n) * CAH;
        float s = 0.f;
        #pragma unroll
        for (int q = 0; q < CAH / 64; ++q) {
            const int d = lane + q * 64;
            s += alpha_w[d] * tanhf(pr[d] + shq[d]);
        }
        for (int off = 32; off; off >>= 1) s += __shfl_down(s, off);
        if (lane == 0) se[n] = s + alpha_b[0];
    }
    __syncthreads();

    float mx = -1e30f;
    for (int n = 0; n < CNREG; ++n) mx = fmaxf(mx, se[n]);
    float sum = 0.f;
    for (int n = 0; n < CNREG; ++n) sum += expf(se[n] - mx);
    const float inv = 1.f / sum;
    if (tid < CNREG) salpha[tid] = expf(se[tid] - mx) * inv;
    __syncthreads();

    for (int d = tid; d < CFE; d += 256) {
        float s = 0.f;
        const bf16_t* ae = att_e + (size_t)b * CNREG * CFE + d;
        #pragma unroll 4
        for (int n = 0; n < CNREG; ++n) s = fmaf(salpha[n], (float)ae[(size_t)n * CFE], s);
        x_lang[(size_t)b * XLANG + d] = (bf16_t)s;
    }
}

// ------- log-softmax over V: row = part0 + part1 (bias already in part0) --------
__global__ __launch_bounds__(256)
void logsoftmax_kernel(const float* __restrict__ p0, const float* __restrict__ p1,
                       float* __restrict__ out_t, int out_ld)
{
    __shared__ float red[4];
    const int b = blockIdx.x, tid = threadIdx.x;
    const float* r0 = p0 + (size_t)b * CVP;
    const float* r1 = p1 + (size_t)b * CVP;

    float mx = -1e30f;
    for (int j = tid; j < CV; j += 256) mx = fmaxf(mx, r0[j] + r1[j]);
    for (int off = 32; off; off >>= 1) mx = fmaxf(mx, __shfl_down(mx, off));
    if ((tid & 63) == 0) red[tid >> 6] = mx;
    __syncthreads();
    mx = fmaxf(fmaxf(red[0], red[1]), fmaxf(red[2], red[3]));
    __syncthreads();

    float sum = 0.f;
    for (int j = tid; j < CV; j += 256) sum += expf(r0[j] + r1[j] - mx);
    for (int off = 32; off; off >>= 1) sum += __shfl_down(sum, off);
    if ((tid & 63) == 0) red[tid >> 6] = sum;
    __syncthreads();
    sum = red[0] + red[1] + red[2] + red[3];
    const float lse = mx + logf(sum);

    float* orow = out_t + (size_t)b * out_ld;
    for (int j = tid; j < CV; j += 256) orow[j] = r0[j] + r1[j] - lse;
}

// ---------------- launch ----------------
extern "C" void kernel_launch(void* const* d_in, const int* in_sizes, int n_in,
                              void* d_out, int out_size, void* d_ws, size_t ws_size,
                              hipStream_t stream)
{
    const float* fc_feats  = (const float*)d_in[0];
    const float* att_feats = (const float*)d_in[1];
    const int*   captions  = (const int*)  d_in[2];
    const float* emb_w     = (const float*)d_in[3];
    const float* fc_w      = (const float*)d_in[4];
    const float* fc_b      = (const float*)d_in[5];
    const float* atte_w    = (const float*)d_in[6];
    const float* atte_b    = (const float*)d_in[7];
    const float* ctx_w     = (const float*)d_in[8];
    const float* ctx_b     = (const float*)d_in[9];
    const float* attl_wih  = (const float*)d_in[10];
    const float* attl_whh  = (const float*)d_in[11];
    const float* attl_bih  = (const float*)d_in[12];
    const float* attl_bhh  = (const float*)d_in[13];
    const float* h2att_w   = (const float*)d_in[14];
    const float* h2att_b   = (const float*)d_in[15];
    const float* alpha_w   = (const float*)d_in[16];
    const float* alpha_b   = (const float*)d_in[17];
    const float* langl_wih = (const float*)d_in[18];
    const float* langl_whh = (const float*)d_in[19];
    const float* langl_bih = (const float*)d_in[20];
    const float* langl_bhh = (const float*)d_in[21];
    const float* cls_w     = (const float*)d_in[22];
    const float* cls_b     = (const float*)d_in[23];

    float* out = (float*)d_out;

    // ---- workspace layout ----
    char* p = (char*)d_ws;
    auto alloc_bf = [&](size_t elems) { bf16_t* q = (bf16_t*)p; p += elems * 2; return q; };
    auto alloc_f  = [&](size_t elems) { float*  q = (float*) p; p += elems * 4; return q; };

    bf16_t* attl_wih_b  = alloc_bf((size_t)G4 * XATT_P);
    bf16_t* attl_whh_b  = alloc_bf((size_t)G4 * CH);
    bf16_t* langl_wih_b = alloc_bf((size_t)G4 * XLANG);
    bf16_t* langl_whh_b = alloc_bf((size_t)G4 * CH);
    bf16_t* fc_wT_b     = alloc_bf((size_t)CFE * CFEAT);
    bf16_t* atte_wT_b   = alloc_bf((size_t)CFE * CFEAT);
    bf16_t* ctx_wT_b    = alloc_bf((size_t)CAH * CFE);
    bf16_t* h2att_wT_b  = alloc_bf((size_t)CAH * CH);
    bf16_t* cls_wT_b    = alloc_bf((size_t)CVP * CH);       // padded rows
    bf16_t* fc_feats_b  = alloc_bf((size_t)CB * CFEAT);
    bf16_t* att_feats_b = alloc_bf((size_t)CB * CNREG * CFEAT);
    bf16_t* att_e_b     = alloc_bf((size_t)CB * CNREG * CFE);
    bf16_t* x_att       = alloc_bf((size_t)CB * XATT_P);
    bf16_t* x_lang      = alloc_bf((size_t)CB * XLANG);
    bf16_t* h_att_b     = alloc_bf((size_t)CB * CH);
    float*  p_att       = alloc_f ((size_t)CB * CNREG * CAH);
    float*  gpart       = alloc_f ((size_t)4 * CB * G4);    // 4-way split-K gate partials
    float*  cpart       = alloc_f ((size_t)2 * CB * CVP);   // 2-way split-K cls partials
    float*  c_att       = alloc_f ((size_t)CB * CH);
    float*  c_lang      = alloc_f ((size_t)CB * CH);

    // ---- zero recurrent state + pads ----
    hipMemsetAsync(x_att,   0, (size_t)CB * XATT_P * 2, stream);
    hipMemsetAsync(h_att_b, 0, (size_t)CB * CH * 2, stream);
    hipMemsetAsync(c_att,   0, (size_t)CB * CH * 4, stream);
    hipMemsetAsync(c_lang,  0, (size_t)CB * CH * 4, stream);
    hipMemsetAsync(cls_wT_b + (size_t)CV * CH, 0, (size_t)(CVP - CV) * CH * 2, stream);

    const dim3 blk(256);

    // ---- one-time conversions ----
    convert_pad<<<dim3(CDIV(XATT_P,256), G4), blk, 0, stream>>>(attl_wih, attl_wih_b, XATT_P-24, XATT_P);
    convert_pad<<<dim3(CDIV(CH,256),    G4), blk, 0, stream>>>(attl_whh, attl_whh_b, CH, CH);
    convert_pad<<<dim3(CDIV(XLANG,256), G4), blk, 0, stream>>>(langl_wih, langl_wih_b, XLANG, XLANG);
    convert_pad<<<dim3(CDIV(CH,256),    G4), blk, 0, stream>>>(langl_whh, langl_whh_b, CH, CH);
    convert_pad<<<dim3(CDIV(CFEAT,256), CB), blk, 0, stream>>>(fc_feats, fc_feats_b, CFEAT, CFEAT);
    convert_pad<<<dim3(CDIV(CFEAT,256), CB*CNREG), blk, 0, stream>>>(att_feats, att_feats_b, CFEAT, CFEAT);
    transpose_convert<<<dim3(CFE/32,  CFEAT/32), blk, 0, stream>>>(fc_w,    fc_wT_b,    CFEAT, CFE);
    transpose_convert<<<dim3(CFE/32,  CFEAT/32), blk, 0, stream>>>(atte_w,  atte_wT_b,  CFEAT, CFE);
    transpose_convert<<<dim3(CAH/32,  CFE/32),   blk, 0, stream>>>(ctx_w,   ctx_wT_b,   CFE,   CAH);
    transpose_convert<<<dim3(CAH/32,  CH/32),    blk, 0, stream>>>(h2att_w, h2att_wT_b, CH,    CAH);
    transpose_convert<<<dim3(CDIV(CV,32), CH/32), blk, 0, stream>>>(cls_w,  cls_wT_b,   CH,    CV);

    // ---- preamble GEMMs ----
    // fc_e = relu(fc_feats @ fc_w + fc_b) -> x_att[:, 1024:2048] (bf16)
    gemm2<false,true,true><<<dim3(CFE/64, CB/128, 1), blk, 0, stream>>>(
        fc_feats_b, CFEAT, fc_wT_b, CFEAT, CFEAT,
        nullptr, 0, nullptr, 0, 0, fc_b, nullptr, x_att + CH, XATT_P, 0);
    // att_e = relu(att_feats @ atte_w + atte_b) (bf16) [4608,1024]
    gemm2<false,true,true><<<dim3(CFE/64, CB*CNREG/128, 1), blk, 0, stream>>>(
        att_feats_b, CFEAT, atte_wT_b, CFEAT, CFEAT,
        nullptr, 0, nullptr, 0, 0, atte_b, nullptr, att_e_b, CFE, 0);
    // p_att = att_e @ ctx_w + ctx_b (fp32) [4608,512]
    gemm2<false,false,false><<<dim3(CAH/64, CB*CNREG/128, 1), blk, 0, stream>>>(
        att_e_b, CFE, ctx_wT_b, CFE, CFE,
        nullptr, 0, nullptr, 0, 0, ctx_b, nullptr, p_att, CAH, 0);

    for (int t = 0; t < CT - 1; ++t) {
        emb_kernel<<<dim3(CDIV(CWE,256), CB), blk, 0, stream>>>(emb_w, captions, t, x_att);

        // att-LSTM gates (split-K=4, partials)
        gemm2<true,false,false><<<dim3(G4/64, 1, 4), blk, 0, stream>>>(
            x_att, XATT_P, attl_wih_b, XATT_P, XATT_P,
            h_att_b, CH, attl_whh_b, CH, CH,
            attl_bih, attl_bhh, gpart, G4, (size_t)CB * G4);

        lstm_kernel<<<CDIV(CB*CH,256), blk, 0, stream>>>(
            gpart, 4, c_att, h_att_b, CH, x_lang + CFE, XLANG);

        attn_kernel<<<CB, blk, 0, stream>>>(
            p_att, h_att_b, h2att_wT_b, h2att_b, att_e_b, alpha_w, alpha_b, x_lang);

        // lang-LSTM gates (old h_lang in x_att[:, 0:1024])
        gemm2<true,false,false><<<dim3(G4/64, 1, 4), blk, 0, stream>>>(
            x_lang, XLANG, langl_wih_b, XLANG, XLANG,
            x_att, XATT_P, langl_whh_b, CH, CH,
            langl_bih, langl_bhh, gpart, G4, (size_t)CB * G4);

        lstm_kernel<<<CDIV(CB*CH,256), blk, 0, stream>>>(
            gpart, 4, c_lang, x_att, XATT_P, nullptr, 0);

        // logits partials (split-K=2), N padded to 12032
        gemm2<false,false,false><<<dim3(CVP/64, 1, 2), blk, 0, stream>>>(
            x_att, XATT_P, cls_wT_b, CH, CH,
            nullptr, 0, nullptr, 0, 0, cls_b, nullptr, cpart, CVP, (size_t)CB * CVP);

        logsoftmax_kernel<<<CB, blk, 0, stream>>>(
            cpart, cpart + (size_t)CB * CVP, out + (size_t)t * CV, (CT - 1) * CV);
    }
}

// Round 4
// 3151.038 us; speedup vs baseline: 3.9283x; 1.1257x over previous
//
#include <hip/hip_runtime.h>
#include <cstddef>
#include <cstdint>

// ---------------- problem constants ----------------
constexpr int CV    = 12000;
constexpr int CVP   = 12032;   // vocab padded to x64
constexpr int CWE   = 1000;
constexpr int CFEAT = 2048;
constexpr int CFE   = 1024;
constexpr int CH    = 1024;
constexpr int CAH   = 512;
constexpr int CNREG = 36;
constexpr int CB    = 128;
constexpr int CT    = 17;
constexpr int XBA   = 2048;    // xba = [h_lang | fc_e]
constexpr int XLG   = 2048;    // x_lang = [att_res | h_att]
constexpr int G4    = 4096;

#define CDIV(a,b) (((a)+(b)-1)/(b))

typedef __bf16 bf16_t;
typedef __bf16 bf16x8 __attribute__((ext_vector_type(8)));
typedef float  f32x4  __attribute__((ext_vector_type(4)));

struct Seg { const bf16_t* A; const bf16_t* W; int lda, ldw, kt; };

// ---------------- multi-segment LDS-staged double-buffered MFMA GEMM ----------
// C[M,N] = sum_seg A_s @ W_s^T + bias1 + bias2. A bf16 [M,lda] row-major,
// W bf16 [N,ldw] row-major. M%128==0 (in-step M=128), N%64==0, K%64==0.
// Block 128x64, 4 waves 2x2, wave 64x32, mfma 16x16x32.
// Split-K via gridDim.z -> fp32 partials at Cout + z*partStride (bias in z==0).
// SWZ: 1D grid, XCD-chunked decode (same-N blocks cluster per XCD for L2 reuse).
template<int NSEG, bool RELU, bool OUTBF, bool SWZ>
__global__ __launch_bounds__(256)
void gemm3(Seg s0, Seg s1, Seg s2, int mblocks,
           const float* __restrict__ bias1, const float* __restrict__ bias2,
           void* __restrict__ Cout, int ldc, size_t partStride)
{
    const int tid = threadIdx.x;
    const int wid = tid >> 6, lane = tid & 63;
    const int wr = wid >> 1, wc = wid & 1;
    const int llo = lane & 15, lhi = lane >> 4;
    int m0, n0;
    if (SWZ) {
        const int nb = gridDim.x, id = blockIdx.x;
        const int sw = (id & 7) * (nb >> 3) + (id >> 3);   // nb % 8 == 0
        n0 = (sw / mblocks) * 64;
        m0 = (sw % mblocks) * 128;
    } else {
        m0 = blockIdx.y * 128;
        n0 = blockIdx.x * 64;
    }
    const int z = blockIdx.z, ns = gridDim.z;

    __shared__ __align__(16) uint8_t sm[2][24576];  // A [0,16384) | B [16384,24576)

    const int TT = s0.kt + (NSEG > 1 ? s1.kt : 0) + (NSEG > 2 ? s2.kt : 0);
    const int tb = (int)(((long)TT * z) / ns), te = (int)(((long)TT * (z + 1)) / ns);

    f32x4 acc[4][2] = {};
    uint4 ra[4], rb[2];

    const int srow = tid >> 3;          // 0..31
    const int sc   = tid & 7;           // 16B chunk index
    const int cswz = (sc ^ (srow & 7)) << 4;

    auto load_tile = [&](int ti) {
        const bf16_t* As = s0.A; const bf16_t* Ws = s0.W;
        int la = s0.lda, lw = s0.ldw, rt = ti;
        if (NSEG > 1 && rt >= s0.kt) {
            rt -= s0.kt; As = s1.A; Ws = s1.W; la = s1.lda; lw = s1.ldw;
            if (NSEG > 2 && rt >= s1.kt) {
                rt -= s1.kt; As = s2.A; Ws = s2.W; la = s2.lda; lw = s2.ldw;
            }
        }
        const int k0 = rt << 6;
        #pragma unroll
        for (int i = 0; i < 4; ++i)
            ra[i] = *(const uint4*)(As + (size_t)(m0 + i * 32 + srow) * la + k0 + sc * 8);
        #pragma unroll
        for (int i = 0; i < 2; ++i)
            rb[i] = *(const uint4*)(Ws + (size_t)(n0 + i * 32 + srow) * lw + k0 + sc * 8);
    };
    auto write_tile = [&](int buf) {
        uint8_t* base = sm[buf];
        #pragma unroll
        for (int i = 0; i < 4; ++i)
            *(uint4*)(base + (i * 32 + srow) * 128 + cswz) = ra[i];
        #pragma unroll
        for (int i = 0; i < 2; ++i)
            *(uint4*)(base + 16384 + (i * 32 + srow) * 128 + cswz) = rb[i];
    };
    auto compute = [&](int buf) {
        const uint8_t* base = sm[buf];
        const int r7 = llo & 7;
        #pragma unroll
        for (int kk = 0; kk < 2; ++kk) {
            const int cp = kk * 4 + lhi;          // permuted-k chunk (same map A & B)
            const int coff = ((cp ^ r7) << 4);
            bf16x8 af[4], bg[2];
            #pragma unroll
            for (int fm = 0; fm < 4; ++fm)
                af[fm] = *(const bf16x8*)(base + (wr * 64 + fm * 16 + llo) * 128 + coff);
            #pragma unroll
            for (int fn = 0; fn < 2; ++fn)
                bg[fn] = *(const bf16x8*)(base + 16384 + (wc * 32 + fn * 16 + llo) * 128 + coff);
            #pragma unroll
            for (int fm = 0; fm < 4; ++fm)
                #pragma unroll
                for (int fn = 0; fn < 2; ++fn)
                    acc[fm][fn] = __builtin_amdgcn_mfma_f32_16x16x32_bf16(
                        af[fm], bg[fn], acc[fm][fn], 0, 0, 0);
        }
    };

    load_tile(tb);
    write_tile(0);
    __syncthreads();
    int cur = 0;
    for (int ti = tb; ti < te; ++ti) {
        const bool more = (ti + 1 < te);
        if (more) load_tile(ti + 1);
        compute(cur);
        __syncthreads();
        if (more) write_tile(cur ^ 1);
        __syncthreads();
        cur ^= 1;
    }

    // epilogue: C/D layout col = lane&15, row = (lane>>4)*4 + reg
    const int colb = n0 + wc * 32;
    const int rowb = m0 + wr * 64 + lhi * 4;
    if (ns > 1) {
        float* Cp = (float*)Cout + (size_t)z * partStride;
        #pragma unroll
        for (int fn = 0; fn < 2; ++fn) {
            const int col = colb + fn * 16 + llo;
            const float b = (z == 0) ? ((bias1 ? bias1[col] : 0.f) + (bias2 ? bias2[col] : 0.f)) : 0.f;
            #pragma unroll
            for (int fm = 0; fm < 4; ++fm)
                #pragma unroll
                for (int r = 0; r < 4; ++r)
                    Cp[(size_t)(rowb + fm * 16 + r) * ldc + col] = acc[fm][fn][r] + b;
        }
    } else {
        #pragma unroll
        for (int fn = 0; fn < 2; ++fn) {
            const int col = colb + fn * 16 + llo;
            float b = 0.f;
            if (bias1) b += bias1[col];
            if (bias2) b += bias2[col];
            #pragma unroll
            for (int fm = 0; fm < 4; ++fm)
                #pragma unroll
                for (int r = 0; r < 4; ++r) {
                    float v = acc[fm][fn][r] + b;
                    if (RELU) v = fmaxf(v, 0.f);
                    const size_t off = (size_t)(rowb + fm * 16 + r) * ldc + col;
                    if (OUTBF) ((bf16_t*)Cout)[off] = (bf16_t)v;
                    else       ((float*) Cout)[off] = v;
                }
        }
    }
}

// ---------------- fp32 -> bf16 convert with column pad ----------------
__global__ void convert_pad(const float* __restrict__ src, bf16_t* __restrict__ dst,
                            int C, int Cp)
{
    const int r = blockIdx.y;
    const int c = blockIdx.x * 256 + threadIdx.x;
    if (c >= Cp) return;
    dst[(size_t)r * Cp + c] = (c < C) ? (bf16_t)src[(size_t)r * C + c] : (bf16_t)0.f;
}

// ---------------- fp32 [K,N] -> bf16 [N,K] transpose-convert ----------------
__global__ __launch_bounds__(256)
void transpose_convert(const float* __restrict__ src, bf16_t* __restrict__ dst,
                       int K, int N)
{
    __shared__ float tile[32][33];
    const int n0 = blockIdx.x * 32, k0 = blockIdx.y * 32;
    const int tx = threadIdx.x & 31, ty = threadIdx.x >> 5;   // 32 x 8
    #pragma unroll
    for (int i = 0; i < 4; ++i) {
        const int k = k0 + ty + i * 8, n = n0 + tx;
        tile[ty + i * 8][tx] = (k < K && n < N) ? src[(size_t)k * N + n] : 0.f;
    }
    __syncthreads();
    #pragma unroll
    for (int i = 0; i < 4; ++i) {
        const int n = n0 + ty + i * 8, k = k0 + tx;
        if (n < N && k < K) dst[(size_t)n * K + k] = (bf16_t)tile[tx][ty + i * 8];
    }
}

// ------- all-timestep embedding gather + relu + pad -> w_all[16][128][1024] -----
__global__ void emb_all(const float* __restrict__ emb_w,
                        const int* __restrict__ captions, bf16_t* __restrict__ w_all)
{
    const int r = blockIdx.y;                       // t*128 + b
    const int j = blockIdx.x * 256 + threadIdx.x;   // 0..1023
    const int t = r >> 7, b = r & 127;
    const int tok = captions[b * CT + t];
    const float v = (j < CWE) ? fmaxf(emb_w[(size_t)tok * CWE + j], 0.f) : 0.f;
    w_all[(size_t)r * 1024 + j] = (bf16_t)v;
}

// ------ fused: reduce 8 gate partials -> att-LSTM -> hq -> attention -----------
// block b handles batch row b end-to-end. writes h_att -> x_lang[:,1024:2048],
// att_res -> x_lang[:,0:1024].
__global__ __launch_bounds__(256)
void lstm_attn(const float* __restrict__ gpart, float* __restrict__ c_att,
               const float* __restrict__ p_att, const bf16_t* __restrict__ att_e,
               const bf16_t* __restrict__ h2att_wT, const float* __restrict__ h2att_b,
               const float* __restrict__ alpha_w, const float* __restrict__ alpha_b,
               bf16_t* __restrict__ x_lang)
{
    __shared__ float h[CH];
    __shared__ float shq[CAH];
    __shared__ float se[CNREG], salpha[CNREG];
    const int b = blockIdx.x, tid = threadIdx.x;

    #pragma unroll
    for (int k = 0; k < 4; ++k) {
        const int j = tid + k * 256;
        float g0 = 0.f, g1 = 0.f, g2 = 0.f, g3 = 0.f;
        #pragma unroll
        for (int z = 0; z < 8; ++z) {
            const float* gp = gpart + (size_t)z * CB * G4 + (size_t)b * G4 + j;
            g0 += gp[0]; g1 += gp[1024]; g2 += gp[2048]; g3 += gp[3072];
        }
        const float si = 1.f / (1.f + expf(-g0));
        const float sf = 1.f / (1.f + expf(-g1));
        const float so = 1.f / (1.f + expf(-g3));
        const float cn = sf * c_att[b * CH + j] + si * tanhf(g2);
        const float hn = so * tanhf(cn);
        c_att[b * CH + j] = cn;
        h[j] = hn;
        x_lang[(size_t)b * XLG + CH + j] = (bf16_t)hn;
    }
    __syncthreads();

    for (int n = tid; n < CAH; n += 256) {
        const bf16_t* wr = h2att_wT + (size_t)n * CH;
        float s = 0.f;
        for (int k = 0; k < CH; k += 8) {
            bf16x8 w8 = *(const bf16x8*)(wr + k);
            #pragma unroll
            for (int q = 0; q < 8; ++q) s = fmaf((float)w8[q], h[k + q], s);
        }
        shq[n] = s + h2att_b[n];
    }
    __syncthreads();

    const int wave = tid >> 6, lane = tid & 63;
    for (int n = wave; n < CNREG; n += 4) {
        const float* pr = p_att + ((size_t)b * CNREG + n) * CAH;
        float s = 0.f;
        #pragma unroll
        for (int q = 0; q < CAH / 64; ++q) {
            const int d = lane + q * 64;
            s += alpha_w[d] * tanhf(pr[d] + shq[d]);
        }
        for (int off = 32; off; off >>= 1) s += __shfl_down(s, off);
        if (lane == 0) se[n] = s + alpha_b[0];
    }
    __syncthreads();

    float mx = -1e30f;
    for (int n = 0; n < CNREG; ++n) mx = fmaxf(mx, se[n]);
    float sum = 0.f;
    for (int n = 0; n < CNREG; ++n) sum += expf(se[n] - mx);
    if (tid < CNREG) salpha[tid] = expf(se[tid] - mx) / sum;
    __syncthreads();

    for (int d = tid; d < CFE; d += 256) {
        float s = 0.f;
        const bf16_t* ae = att_e + (size_t)b * CNREG * CFE + d;
        #pragma unroll 4
        for (int n = 0; n < CNREG; ++n) s = fmaf(salpha[n], (float)ae[(size_t)n * CFE], s);
        x_lang[(size_t)b * XLG + d] = (bf16_t)s;
    }
}

// ---------- flat lang-LSTM: reduce 8 partials -> c_lang, h_lang bf16 -----------
__global__ void lstm_flat(const float* __restrict__ gpart, float* __restrict__ c,
                          bf16_t* __restrict__ h1, int ld1)
{
    const int idx = blockIdx.x * 256 + threadIdx.x;
    if (idx >= CB * CH) return;
    const int b = idx >> 10, j = idx & (CH - 1);
    float g0 = 0.f, g1 = 0.f, g2 = 0.f, g3 = 0.f;
    #pragma unroll
    for (int z = 0; z < 8; ++z) {
        const float* gp = gpart + (size_t)z * CB * G4 + (size_t)b * G4 + j;
        g0 += gp[0]; g1 += gp[1024]; g2 += gp[2048]; g3 += gp[3072];
    }
    const float si = 1.f / (1.f + expf(-g0));
    const float sf = 1.f / (1.f + expf(-g1));
    const float so = 1.f / (1.f + expf(-g3));
    const float cn = sf * c[idx] + si * tanhf(g2);
    const float hn = so * tanhf(cn);
    c[idx] = cn;
    h1[(size_t)b * ld1 + j] = (bf16_t)hn;
}

// ------ single-pass log-softmax: sum 4 fp32 partials, registers-resident -------
__global__ __launch_bounds__(256)
void logsoftmax4(const float* __restrict__ cp, float* __restrict__ out_t, int out_ld)
{
    __shared__ float red[4];
    const int b = blockIdx.x, tid = threadIdx.x;
    const float* r0 = cp + (size_t)b * CVP;
    const size_t PS = (size_t)CB * CVP;
    constexpr int NI = 47;   // 47*256 = 12032

    float v[NI];
    float mx = -1e30f;
    #pragma unroll
    for (int i = 0; i < NI; ++i) {
        const int j = tid + i * 256;
        if (j < CV) {
            const float s = r0[j] + r0[j + PS] + r0[j + 2 * PS] + r0[j + 3 * PS];
            v[i] = s;
            mx = fmaxf(mx, s);
        } else v[i] = -1e30f;
    }
    for (int off = 32; off; off >>= 1) mx = fmaxf(mx, __shfl_down(mx, off));
    if ((tid & 63) == 0) red[tid >> 6] = mx;
    __syncthreads();
    mx = fmaxf(fmaxf(red[0], red[1]), fmaxf(red[2], red[3]));
    __syncthreads();

    float sum = 0.f;
    #pragma unroll
    for (int i = 0; i < NI; ++i)
        if (tid + i * 256 < CV) sum += expf(v[i] - mx);
    for (int off = 32; off; off >>= 1) sum += __shfl_down(sum, off);
    if ((tid & 63) == 0) red[tid >> 6] = sum;
    __syncthreads();
    sum = red[0] + red[1] + red[2] + red[3];
    const float lse = mx + logf(sum);

    float* orow = out_t + (size_t)b * out_ld;
    #pragma unroll
    for (int i = 0; i < NI; ++i) {
        const int j = tid + i * 256;
        if (j < CV) orow[j] = v[i] - lse;
    }
}

// ---------------- launch ----------------
extern "C" void kernel_launch(void* const* d_in, const int* in_sizes, int n_in,
                              void* d_out, int out_size, void* d_ws, size_t ws_size,
                              hipStream_t stream)
{
    const float* fc_feats  = (const float*)d_in[0];
    const float* att_feats = (const float*)d_in[1];
    const int*   captions  = (const int*)  d_in[2];
    const float* emb_w     = (const float*)d_in[3];
    const float* fc_w      = (const float*)d_in[4];
    const float* fc_b      = (const float*)d_in[5];
    const float* atte_w    = (const float*)d_in[6];
    const float* atte_b    = (const float*)d_in[7];
    const float* ctx_w     = (const float*)d_in[8];
    const float* ctx_b     = (const float*)d_in[9];
    const float* attl_wih  = (const float*)d_in[10];
    const float* attl_whh  = (const float*)d_in[11];
    const float* attl_bih  = (const float*)d_in[12];
    const float* attl_bhh  = (const float*)d_in[13];
    const float* h2att_w   = (const float*)d_in[14];
    const float* h2att_b   = (const float*)d_in[15];
    const float* alpha_w   = (const float*)d_in[16];
    const float* alpha_b   = (const float*)d_in[17];
    const float* langl_wih = (const float*)d_in[18];
    const float* langl_whh = (const float*)d_in[19];
    const float* langl_bih = (const float*)d_in[20];
    const float* langl_bhh = (const float*)d_in[21];
    const float* cls_w     = (const float*)d_in[22];
    const float* cls_b     = (const float*)d_in[23];

    float* out = (float*)d_out;

    // ---- workspace layout ----
    char* p = (char*)d_ws;
    auto alloc_bf = [&](size_t e) { bf16_t* q = (bf16_t*)p; p += e * 2; return q; };
    auto alloc_f  = [&](size_t e) { float*  q = (float*) p; p += e * 4; return q; };

    bf16_t* attl_wih_b  = alloc_bf((size_t)G4 * 3072);      // [4096][3072] (24 pad cols 0)
    bf16_t* attl_whh_b  = alloc_bf((size_t)G4 * CH);
    bf16_t* langl_wih_b = alloc_bf((size_t)G4 * 2048);
    bf16_t* langl_whh_b = alloc_bf((size_t)G4 * CH);
    bf16_t* fc_wT_b     = alloc_bf((size_t)CFE * CFEAT);
    bf16_t* atte_wT_b   = alloc_bf((size_t)CFE * CFEAT);
    bf16_t* ctx_wT_b    = alloc_bf((size_t)CAH * CFE);
    bf16_t* h2att_wT_b  = alloc_bf((size_t)CAH * CH);
    bf16_t* cls_wT_b    = alloc_bf((size_t)CVP * CH);
    bf16_t* fc_feats_b  = alloc_bf((size_t)CB * CFEAT);
    bf16_t* att_feats_b = alloc_bf((size_t)CB * CNREG * CFEAT);
    bf16_t* att_e_b     = alloc_bf((size_t)CB * CNREG * CFE);
    bf16_t* w_all       = alloc_bf((size_t)(CT - 1) * CB * 1024);
    bf16_t* xba         = alloc_bf((size_t)CB * XBA);       // [h_lang | fc_e]
    bf16_t* x_lang      = alloc_bf((size_t)CB * XLG);       // [att_res | h_att]
    float*  p_att       = alloc_f ((size_t)CB * CNREG * CAH);
    float*  gpart       = alloc_f ((size_t)8 * CB * G4);
    float*  cpart       = alloc_f ((size_t)4 * CB * CVP);
    float*  c_att       = alloc_f ((size_t)CB * CH);
    float*  c_lang      = alloc_f ((size_t)CB * CH);

    // ---- zero state ----
    hipMemsetAsync(xba,    0, (size_t)CB * XBA * 2, stream);
    hipMemsetAsync(x_lang, 0, (size_t)CB * XLG * 2, stream);
    hipMemsetAsync(c_att,  0, (size_t)CB * CH * 4, stream);
    hipMemsetAsync(c_lang, 0, (size_t)CB * CH * 4, stream);
    hipMemsetAsync(cls_wT_b + (size_t)CV * CH, 0, (size_t)(CVP - CV) * CH * 2, stream);

    const dim3 blk(256);
    const Seg z0{nullptr, nullptr, 0, 0, 0};
    auto mk = [](const bf16_t* A, int lda, const bf16_t* W, int ldw, int K) {
        return Seg{A, W, lda, ldw, K >> 6};
    };

    // ---- one-time conversions ----
    convert_pad<<<dim3(12, G4), blk, 0, stream>>>(attl_wih, attl_wih_b, 3048, 3072);
    convert_pad<<<dim3(4,  G4), blk, 0, stream>>>(attl_whh, attl_whh_b, CH, CH);
    convert_pad<<<dim3(8,  G4), blk, 0, stream>>>(langl_wih, langl_wih_b, 2048, 2048);
    convert_pad<<<dim3(4,  G4), blk, 0, stream>>>(langl_whh, langl_whh_b, CH, CH);
    convert_pad<<<dim3(8,  CB), blk, 0, stream>>>(fc_feats, fc_feats_b, CFEAT, CFEAT);
    convert_pad<<<dim3(8,  CB * CNREG), blk, 0, stream>>>(att_feats, att_feats_b, CFEAT, CFEAT);
    transpose_convert<<<dim3(CFE/32, CFEAT/32), blk, 0, stream>>>(fc_w,    fc_wT_b,    CFEAT, CFE);
    transpose_convert<<<dim3(CFE/32, CFEAT/32), blk, 0, stream>>>(atte_w,  atte_wT_b,  CFEAT, CFE);
    transpose_convert<<<dim3(CAH/32, CFE/32),   blk, 0, stream>>>(ctx_w,   ctx_wT_b,   CFE,   CAH);
    transpose_convert<<<dim3(CAH/32, CH/32),    blk, 0, stream>>>(h2att_w, h2att_wT_b, CH,    CAH);
    transpose_convert<<<dim3(CDIV(CV,32), CH/32), blk, 0, stream>>>(cls_w, cls_wT_b,   CH,    CV);
    emb_all<<<dim3(4, (CT - 1) * CB), blk, 0, stream>>>(emb_w, captions, w_all);

    // ---- preamble GEMMs (XCD-swizzled 1D grids) ----
    // fc_e -> xba[:, 1024:2048]
    gemm3<1,true,true,true><<<16, blk, 0, stream>>>(
        mk(fc_feats_b, CFEAT, fc_wT_b, CFEAT, CFEAT), z0, z0, 1,
        fc_b, nullptr, xba + CH, XBA, 0);
    // att_e = relu(att_feats @ atte_w + b)  [4608,1024] bf16
    gemm3<1,true,true,true><<<576, blk, 0, stream>>>(
        mk(att_feats_b, CFEAT, atte_wT_b, CFEAT, CFEAT), z0, z0, 36,
        atte_b, nullptr, att_e_b, CFE, 0);
    // p_att = att_e @ ctx_w + b  [4608,512] fp32
    gemm3<1,false,false,true><<<288, blk, 0, stream>>>(
        mk(att_e_b, CFE, ctx_wT_b, CFE, CFE), z0, z0, 36,
        ctx_b, nullptr, p_att, CAH, 0);

    for (int t = 0; t < CT - 1; ++t) {
        // att-LSTM gates: [h_lang|fc_e] (+) w_t (+) h_att, split-K=8
        gemm3<3,false,false,false><<<dim3(G4/64, 1, 8), blk, 0, stream>>>(
            mk(xba, XBA, attl_wih_b, 3072, 2048),
            mk(w_all + (size_t)t * CB * 1024, 1024, attl_wih_b + 2048, 3072, 1024),
            mk(x_lang + CH, XLG, attl_whh_b, CH, CH),
            0, attl_bih, attl_bhh, gpart, G4, (size_t)CB * G4);

        // fused reduce + att-LSTM + hq + attention
        lstm_attn<<<CB, blk, 0, stream>>>(
            gpart, c_att, p_att, att_e_b, h2att_wT_b, h2att_b, alpha_w, alpha_b, x_lang);

        // lang-LSTM gates: [att_res|h_att] (+) h_lang, split-K=8
        gemm3<2,false,false,false><<<dim3(G4/64, 1, 8), blk, 0, stream>>>(
            mk(x_lang, XLG, langl_wih_b, 2048, 2048),
            mk(xba, XBA, langl_whh_b, CH, CH),
            z0, 0, langl_bih, langl_bhh, gpart, G4, (size_t)CB * G4);

        // reduce + lang-LSTM -> h_lang into xba[:, 0:1024]
        lstm_flat<<<CDIV(CB*CH, 256), blk, 0, stream>>>(gpart, c_lang, xba, XBA);

        // classifier partials, split-K=4 (A = h_lang = xba[:, 0:1024])
        gemm3<1,false,false,false><<<dim3(CVP/64, 1, 4), blk, 0, stream>>>(
            mk(xba, XBA, cls_wT_b, CH, CH), z0, z0, 0,
            cls_b, nullptr, cpart, CVP, (size_t)CB * CVP);

        logsoftmax4<<<CB, blk, 0, stream>>>(cpart, out + (size_t)t * CV, (CT - 1) * CV);
    }
}